// Round 7
// baseline (412.990 us; speedup 1.0000x reference)
//
#include <hip/hip_runtime.h>
#include <hip/hip_bf16.h>
#include <cstdint>
#include <cstddef>

// ---------------------------------------------------------------------------
// STGNN forward. Round 12: 128x64 GEMM tile + three more launch merges.
//  - R9/R11 post-mortem: launch merging confirmed (-46us, 451->405). Gather
//    back at 104us as predicted; everything else < 104us.
//  - GEMM was ~160-180us aggregate at ~150 TF: 64x64 tile = 4 MFMA per wave
//    between 2 full-drain barriers. New 128x64 tile: 8 MFMA / 6 ds_reads per
//    wave per K-step, acc = 8 x f32x4 = 32 VGPR (R8's failure was 64), LDS
//    15.4KB, col-block y-parallelism kept.
//  - Launch merges: fold_ct -> prep_all (segment), pretransform-c -> one
//    gemm_pre2 launch (y 0..7), alpha_from_fold -> gemm_proj3 (y == 12).
//    10 -> 7 launches.
//  - Gather/buckets untouched (proven form).
// ---------------------------------------------------------------------------

#define LRELU_SLOPE 0.2f
#define CAP 64
#define NRANGE 8

typedef __attribute__((ext_vector_type(8))) short short8;
typedef __attribute__((ext_vector_type(4))) float floatx4;

__device__ __forceinline__ float bf2f(ushort u) {
    union { unsigned int u32; float f; } v; v.u32 = ((unsigned int)u) << 16; return v.f;
}
__device__ __forceinline__ ushort f2bf(float x) {
    union { float f; unsigned int u; } v; v.f = x;
    unsigned int r = (v.u + 0x7FFFu + ((v.u >> 16) & 1u)) >> 16;
    return (ushort)r;
}

// ---- prep_all: casts | 6x weight transpose | fold_ct, one segmented grid ---
__global__ __launch_bounds__(256) void prep_all(
    const float* __restrict__ xt, ushort* __restrict__ xtb,
    const float* __restrict__ xc, ushort* __restrict__ xcb,
    const float* __restrict__ Wt,  ushort* __restrict__ WtT,
    const float* __restrict__ Wc,  ushort* __restrict__ WcT,
    const float* __restrict__ W1,  ushort* __restrict__ W1T,
    const float* __restrict__ W2,  ushort* __restrict__ W2T,
    const float* __restrict__ W3,  ushort* __restrict__ W3T,
    const float* __restrict__ W4,  ushort* __restrict__ W4T,
    const float* __restrict__ Wcd, const float* __restrict__ adc,
    float* __restrict__ wfold,
    int s0, int s1, int s2, int s3, int s4, int s5, int s6, int s7, int s8)
{
    const int idx = blockIdx.x * blockDim.x + threadIdx.x;
    if (idx < s0) {                       // x_target: float4 -> ushort4
        float4 v = ((const float4*)xt)[idx];
        ushort4 o;
        o.x = f2bf(v.x); o.y = f2bf(v.y); o.z = f2bf(v.z); o.w = f2bf(v.w);
        ((ushort4*)xtb)[idx] = o;
    } else if (idx < s1) {                // x_context
        const int i = idx - s0;
        float4 v = ((const float4*)xc)[i];
        ushort4 o;
        o.x = f2bf(v.x); o.y = f2bf(v.y); o.z = f2bf(v.z); o.w = f2bf(v.w);
        ((ushort4*)xcb)[i] = o;
    } else if (idx < s2) {                // Wt [128][256]
        const int i = idx - s1, k = i >> 8, n = i & 255;
        WtT[n * 128 + k] = f2bf(Wt[i]);
    } else if (idx < s3) {                // Wc [64][256]
        const int i = idx - s2, k = i >> 8, n = i & 255;
        WcT[n * 64 + k] = f2bf(Wc[i]);
    } else if (idx < s4) {                // W_s2d [256][256]
        const int i = idx - s3, k = i >> 8, n = i & 255;
        W1T[n * 256 + k] = f2bf(W1[i]);
    } else if (idx < s5) {                // W_d2s
        const int i = idx - s4, k = i >> 8, n = i & 255;
        W2T[n * 256 + k] = f2bf(W2[i]);
    } else if (idx < s6) {                // W_ct_src
        const int i = idx - s5, k = i >> 8, n = i & 255;
        W3T[n * 256 + k] = f2bf(W3[i]);
    } else if (idx < s7) {                // W_out
        const int i = idx - s6, k = i >> 8, n = i & 255;
        W4T[n * 256 + k] = f2bf(W4[i]);
    } else if (idx < s8) {                // fold_ct: wfold[k,h]
        const int i = idx - s7, k = i >> 2, h = i & 3;
        float s = 0.f;
#pragma unroll 8
        for (int c = 0; c < 64; ++c)
            s += Wcd[(size_t)k * 256 + h * 64 + c] * adc[h * 64 + c];
        wfold[i] = s;
    }
}

// ---------------- bf16 MFMA GEMM core, 128x64 tile --------------------------
// 4 waves; wave w owns rows 32w..32w+31 (2 row-frags x 4 col-frags, 8 MFMA
// per K-step). Optional fused attention dots (pre-bias acc).
__device__ __forceinline__ void gemm_core(
    const ushort* __restrict__ A, const ushort* __restrict__ Bt,
    const float* __restrict__ bias, float* __restrict__ Cf,
    ushort* __restrict__ Cb, int M, int K, int do_relu,
    const float* __restrict__ attS, const float* __restrict__ attD,
    float* __restrict__ aSo, float* __restrict__ aDo,
    int row0, int col0)
{
    __shared__ short As[128][40];  // +8 pad
    __shared__ short Bs[64][40];
    const int tid  = threadIdx.x;
    const int ra = tid >> 1;            // A stage: 2 threads/row, 16 cols each
    const int ka = (tid & 1) * 16;
    const int rb = tid >> 2;            // B stage: 4 threads/row, 8 cols each
    const int kb = (tid & 3) * 8;
    const int w    = tid >> 6;
    const int lane = tid & 63;
    const int cix  = lane & 15;
    const int ksel = (lane >> 4) * 8;

    floatx4 acc[2][4];
#pragma unroll
    for (int r = 0; r < 2; ++r)
#pragma unroll
        for (int c = 0; c < 4; ++c) acc[r][c] = (floatx4){0.f, 0.f, 0.f, 0.f};

    for (int k0 = 0; k0 < K; k0 += 32) {
        short8 a0 = {0,0,0,0,0,0,0,0}, a1 = a0;
        if (row0 + ra < M) {
            const ushort* ap = A + (size_t)(row0 + ra) * K + k0 + ka;
            a0 = *(const short8*)ap;
            a1 = *(const short8*)(ap + 8);
        }
        *(short8*)&As[ra][ka]     = a0;
        *(short8*)&As[ra][ka + 8] = a1;
        *(short8*)&Bs[rb][kb] =
            *(const short8*)(Bt + (size_t)(col0 + rb) * K + k0 + kb);
        __syncthreads();
        const short8 af0 = *(const short8*)&As[32 * w + cix][ksel];
        const short8 af1 = *(const short8*)&As[32 * w + 16 + cix][ksel];
#pragma unroll
        for (int c = 0; c < 4; ++c) {
            const short8 bf = *(const short8*)&Bs[16 * c + cix][ksel];
            acc[0][c] = __builtin_amdgcn_mfma_f32_16x16x32_bf16(af0, bf, acc[0][c], 0, 0, 0);
            acc[1][c] = __builtin_amdgcn_mfma_f32_16x16x32_bf16(af1, bf, acc[1][c], 0, 0, 0);
        }
        __syncthreads();
    }

#pragma unroll
    for (int r = 0; r < 2; ++r) {
        const int rbase = row0 + 32 * w + 16 * r + (lane >> 4) * 4;
#pragma unroll
        for (int c = 0; c < 4; ++c) {
            const int col = col0 + 16 * c + cix;
            const float bv = bias ? bias[col] : 0.f;
#pragma unroll
            for (int i = 0; i < 4; ++i) {
                const int row = rbase + i;
                if (row < M) {
                    float v = acc[r][c][i] + bv;
                    if (do_relu) v = fmaxf(v, 0.f);
                    const size_t off = (size_t)row * 256 + col;
                    if (Cf) Cf[off] = v;
                    if (Cb) Cb[off] = f2bf(v);
                }
            }
        }
    }

    // fused per-row attention dots (raw fp32 acc, pre-bias/relu)
    if (attS) {
        float sA[2][4], sD[2][4];
#pragma unroll
        for (int r = 0; r < 2; ++r)
#pragma unroll
            for (int i = 0; i < 4; ++i) { sA[r][i] = 0.f; sD[r][i] = 0.f; }
#pragma unroll
        for (int c = 0; c < 4; ++c) {
            const float as_v = attS[col0 + 16 * c + cix];
            const float ad_v = attD ? attD[col0 + 16 * c + cix] : 0.f;
#pragma unroll
            for (int r = 0; r < 2; ++r)
#pragma unroll
                for (int i = 0; i < 4; ++i) {
                    sA[r][i] += acc[r][c][i] * as_v;
                    sD[r][i] += acc[r][c][i] * ad_v;
                }
        }
#pragma unroll
        for (int off = 1; off < 16; off <<= 1) {
#pragma unroll
            for (int r = 0; r < 2; ++r)
#pragma unroll
                for (int i = 0; i < 4; ++i) {
                    sA[r][i] += __shfl_xor(sA[r][i], off);
                    sD[r][i] += __shfl_xor(sD[r][i], off);
                }
        }
        if (cix == 0) {
            const int head = col0 >> 6;
#pragma unroll
            for (int r = 0; r < 2; ++r) {
                const int rbase = row0 + 32 * w + 16 * r + (lane >> 4) * 4;
#pragma unroll
                for (int i = 0; i < 4; ++i) {
                    const int row = rbase + i;
                    if (row < M) {
                        aSo[(size_t)row * 4 + head] = sA[r][i];
                        if (aDo) aDo[(size_t)row * 4 + head] = sD[r][i];
                    }
                }
            }
        }
    }
}

// ---- standalone GEMM (final linear): grid (M/128, 4) -----------------------
__global__ __launch_bounds__(256) void gemm_bf16(
    const ushort* __restrict__ A, const ushort* __restrict__ Bt,
    const float* __restrict__ bias, float* __restrict__ Cf,
    ushort* __restrict__ Cb, int M, int K, int do_relu)
{
    const int row0 = blockIdx.x * 128;
    if (row0 >= M) return;
    gemm_core(A, Bt, bias, Cf, Cb, M, K, do_relu,
              nullptr, nullptr, nullptr, nullptr, row0, blockIdx.y * 64);
}

// ---- merged pretransforms: y<4 target (K=128), y>=4 context (K=64) ---------
__global__ __launch_bounds__(256) void gemm_pre2(
    const ushort* __restrict__ xtb, const ushort* __restrict__ WtT,
    const float* __restrict__ bt, ushort* __restrict__ htb, int NT,
    const ushort* __restrict__ xcb, const ushort* __restrict__ WcT,
    const float* __restrict__ bc, ushort* __restrict__ hcb, int NC)
{
    const int y = blockIdx.y;
    const int row0 = blockIdx.x * 128;
    if (y < 4) {
        if (row0 >= NT) return;
        gemm_core(xtb, WtT, bt, nullptr, htb, NT, 128, 1,
                  nullptr, nullptr, nullptr, nullptr, row0, y * 64);
    } else {
        if (row0 >= NC) return;
        gemm_core(xcb, WcT, bc, nullptr, hcb, NC, 64, 1,
                  nullptr, nullptr, nullptr, nullptr, row0, (y - 4) * 64);
    }
}

// ---- merged projections: y<4 s2d | y<8 d2s | y<12 ct-src | y==12 alpha -----
__global__ __launch_bounds__(256) void gemm_proj3(
    const ushort* __restrict__ htb, const ushort* __restrict__ hcb,
    const ushort* __restrict__ W1T, const ushort* __restrict__ W2T,
    const ushort* __restrict__ W3T,
    ushort* __restrict__ Pb1, ushort* __restrict__ Pb2, ushort* __restrict__ PSb,
    const float* __restrict__ as1, const float* __restrict__ ad1,
    const float* __restrict__ as2, const float* __restrict__ ad2,
    const float* __restrict__ asc,
    float* __restrict__ aS1, float* __restrict__ aD1,
    float* __restrict__ aS2, float* __restrict__ aD2,
    float* __restrict__ aSc,
    const float* __restrict__ wfold, float* __restrict__ aDc,
    int NT, int NC)
{
    const int y = blockIdx.y;
    if (y == 12) {
        // alpha_from_fold: aDc[n,h] = htb[n,:] . wfold[:,h]
        __shared__ float wf[1024];
        const int tid = threadIdx.x;
        *(float4*)&wf[tid * 4] = *(const float4*)&wfold[tid * 4];
        __syncthreads();
        const int idx = blockIdx.x * 256 + tid;
        if (idx >= NT * 4) return;
        const int n = idx >> 2, h = idx & 3;
        const ushort* row = htb + (size_t)n * 256;
        float s = 0.f;
#pragma unroll
        for (int k = 0; k < 256; k += 4) {
            ushort4 r4 = *(const ushort4*)(row + k);
            s += bf2f(r4.x) * wf[(k + 0) * 4 + h] + bf2f(r4.y) * wf[(k + 1) * 4 + h]
               + bf2f(r4.z) * wf[(k + 2) * 4 + h] + bf2f(r4.w) * wf[(k + 3) * 4 + h];
        }
        aDc[idx] = s;
        return;
    }
    const int row0 = blockIdx.x * 128;
    if (y < 4) {
        if (row0 >= NT) return;
        gemm_core(htb, W1T, nullptr, nullptr, Pb1, NT, 256, 0,
                  as1, ad1, aS1, aD1, row0, y * 64);
    } else if (y < 8) {
        if (row0 >= NT) return;
        gemm_core(htb, W2T, nullptr, nullptr, Pb2, NT, 256, 0,
                  as2, ad2, aS2, aD2, row0, (y - 4) * 64);
    } else {
        if (row0 >= NC) return;
        gemm_core(hcb, W3T, nullptr, nullptr, PSb, NC, 256, 0,
                  asc, nullptr, aSc, nullptr, row0, (y - 8) * 64);
    }
}

// ---- merged topology bucket build: blocks [0,512) tt, [512,1024) ct --------
// XCD-range-partitioned (range = bx&7), int payload (partner node only).
__global__ __launch_bounds__(256) void build_all_buckets(
    const int* __restrict__ tt_src, const int* __restrict__ tt_dst, int E_tt,
    const int* __restrict__ ct_src, const int* __restrict__ ct_dst, int E_ct,
    int RS,
    int* __restrict__ cntA, int* __restrict__ bktA,
    int* __restrict__ cntB, int* __restrict__ bktB,
    int* __restrict__ cntC, int* __restrict__ bktC)
{
    const int bx = (blockIdx.x < 512) ? blockIdx.x : blockIdx.x - 512;
    const int range = bx & (NRANGE - 1);
    const int lo = range * RS, hi = lo + RS;
    const int j  = bx >> 3;                  // 64 blocks per range
    const int stride = 64 * blockDim.x;
    if (blockIdx.x < 512) {
        for (int e = j * blockDim.x + threadIdx.x; e < E_tt; e += stride) {
            const int s = tt_src[e], d = tt_dst[e];
            if (d >= lo && d < hi) {
                const int pa = atomicAdd(&cntA[d], 1);
                if (pa < CAP) bktA[(size_t)d * CAP + pa] = s;
            }
            if (s >= lo && s < hi) {
                const int pb = atomicAdd(&cntB[s], 1);
                if (pb < CAP) bktB[(size_t)s * CAP + pb] = d;
            }
        }
    } else {
        for (int e = j * blockDim.x + threadIdx.x; e < E_ct; e += stride) {
            const int s = ct_src[e], d = ct_dst[e];
            if (d >= lo && d < hi) {
                const int p = atomicAdd(&cntC[d], 1);
                if (p < CAP) bktC[(size_t)d * CAP + p] = s;
            }
        }
    }
}

// ---- one GAT accumulation phase (R7 verbatim; inlined 3x in fused gather) --
__device__ __forceinline__ void gat_phase(
    int n, int h, int c4,
    const int* __restrict__ cnt, const int* __restrict__ bkt,
    const float* __restrict__ aS, const float* __restrict__ aD,
    const ushort* __restrict__ X, const float* __restrict__ bias,
    float scale, int has_self, float4& out)
{
    const float aDn = aD[(size_t)n * 4 + h];
    float4 f = {0.f, 0.f, 0.f, 0.f};
    float den = 0.f;
    if (has_self) {
        float a = aS[(size_t)n * 4 + h] + aDn;
        a = (a >= 0.f) ? a : LRELU_SLOPE * a;
        const float w = __expf(a);
        const ushort4 x = *(const ushort4*)(X + (size_t)n * 256 + c4);
        f.x = w * bf2f(x.x); f.y = w * bf2f(x.y);
        f.z = w * bf2f(x.z); f.w = w * bf2f(x.w);
        den = w;
    }
    const int deg = min(cnt[n], CAP);
    const int* b = bkt + (size_t)n * CAP;
    int i = 0;
    for (; i + 4 <= deg; i += 4) {
        const int s0 = b[i], s1 = b[i + 1], s2 = b[i + 2], s3 = b[i + 3];
        float a0 = aS[(size_t)s0 * 4 + h] + aDn;
        float a1 = aS[(size_t)s1 * 4 + h] + aDn;
        float a2 = aS[(size_t)s2 * 4 + h] + aDn;
        float a3 = aS[(size_t)s3 * 4 + h] + aDn;
        a0 = (a0 >= 0.f) ? a0 : LRELU_SLOPE * a0;
        a1 = (a1 >= 0.f) ? a1 : LRELU_SLOPE * a1;
        a2 = (a2 >= 0.f) ? a2 : LRELU_SLOPE * a2;
        a3 = (a3 >= 0.f) ? a3 : LRELU_SLOPE * a3;
        const float w0 = __expf(a0), w1 = __expf(a1);
        const float w2 = __expf(a2), w3 = __expf(a3);
        const ushort4 x0 = *(const ushort4*)(X + (size_t)s0 * 256 + c4);
        const ushort4 x1 = *(const ushort4*)(X + (size_t)s1 * 256 + c4);
        const ushort4 x2 = *(const ushort4*)(X + (size_t)s2 * 256 + c4);
        const ushort4 x3 = *(const ushort4*)(X + (size_t)s3 * 256 + c4);
        f.x += w0 * bf2f(x0.x) + w1 * bf2f(x1.x) + w2 * bf2f(x2.x) + w3 * bf2f(x3.x);
        f.y += w0 * bf2f(x0.y) + w1 * bf2f(x1.y) + w2 * bf2f(x2.y) + w3 * bf2f(x3.y);
        f.z += w0 * bf2f(x0.z) + w1 * bf2f(x1.z) + w2 * bf2f(x2.z) + w3 * bf2f(x3.z);
        f.w += w0 * bf2f(x0.w) + w1 * bf2f(x1.w) + w2 * bf2f(x2.w) + w3 * bf2f(x3.w);
        den += w0 + w1 + w2 + w3;
    }
    for (; i < deg; ++i) {
        const int s = b[i];
        float a = aS[(size_t)s * 4 + h] + aDn;
        a = (a >= 0.f) ? a : LRELU_SLOPE * a;
        const float w = __expf(a);
        const ushort4 x = *(const ushort4*)(X + (size_t)s * 256 + c4);
        f.x += w * bf2f(x.x); f.y += w * bf2f(x.y);
        f.z += w * bf2f(x.z); f.w += w * bf2f(x.w);
        den += w;
    }
    const float inv = 1.f / fmaxf(den, 1e-16f);
    const float4 bv = *(const float4*)(bias + c4);
    out.x += scale * (f.x * inv + bv.x);
    out.y += scale * (f.y * inv + bv.y);
    out.z += scale * (f.z * inv + bv.z);
    out.w += scale * (f.w * inv + bv.w);
}

// ---- fused gather: all 3 GATs + skip + relu + bf16 cast, one wave/node -----
__global__ __launch_bounds__(256) void gat_gather_fused(
    const int* __restrict__ cntA, const int* __restrict__ bktA,
    const float* __restrict__ aS1, const float* __restrict__ aD1,
    const ushort* __restrict__ P1, const float* __restrict__ b1,
    const int* __restrict__ cntB, const int* __restrict__ bktB,
    const float* __restrict__ aS2, const float* __restrict__ aD2,
    const ushort* __restrict__ P2, const float* __restrict__ b2,
    const int* __restrict__ cntC, const int* __restrict__ bktC,
    const float* __restrict__ aSc, const float* __restrict__ aDc,
    const ushort* __restrict__ Pc, const float* __restrict__ b3,
    ushort* __restrict__ htb, int N)
{
    const int n = blockIdx.x * 4 + (threadIdx.x >> 6);
    if (n >= N) return;
    const int lane = threadIdx.x & 63;
    const int h  = lane >> 4;          // 16 lanes per head
    const int c4 = lane << 2;          // channel base, 0..252

    float4 out = {0.f, 0.f, 0.f, 0.f};
    gat_phase(n, h, c4, cntA, bktA, aS1, aD1, P1, b1, 0.25f, 1, out);
    gat_phase(n, h, c4, cntB, bktB, aS2, aD2, P2, b2, 0.25f, 1, out);
    gat_phase(n, h, c4, cntC, bktC, aSc, aDc, Pc, b3, 0.50f, 0, out);

    ushort* hp = htb + (size_t)n * 256 + c4;
    const ushort4 hb = *(const ushort4*)hp;
    ushort4 o;
    o.x = f2bf(fmaxf(out.x + bf2f(hb.x), 0.f));
    o.y = f2bf(fmaxf(out.y + bf2f(hb.y), 0.f));
    o.z = f2bf(fmaxf(out.z + bf2f(hb.z), 0.f));
    o.w = f2bf(fmaxf(out.w + bf2f(hb.w), 0.f));
    *(ushort4*)hp = o;
}

// ---------------------------------------------------------------------------
extern "C" void kernel_launch(void* const* d_in, const int* in_sizes, int n_in,
                              void* d_out, int out_size, void* d_ws, size_t ws_size,
                              hipStream_t stream)
{
    const int NT   = in_sizes[0] / 128;
    const int NC   = in_sizes[1] / 64;
    const int E_TT = in_sizes[2] / 2;
    const int E_CT = in_sizes[3];

    const float* x_target = (const float*)d_in[0];
    const float* x_context= (const float*)d_in[1];
    const int*   ei_tt    = (const int*)d_in[2];
    const int*   ei_ct_src= (const int*)d_in[3];
    const int*   ei_ct_dst= (const int*)d_in[4];
    const float* Wt   = (const float*)d_in[5];
    const float* bt   = (const float*)d_in[6];
    const float* Wc   = (const float*)d_in[7];
    const float* bc   = (const float*)d_in[8];
    const float* W_s2d  = (const float*)d_in[9];
    const float* as_s2d = (const float*)d_in[10];
    const float* ad_s2d = (const float*)d_in[11];
    const float* b_s2d  = (const float*)d_in[12];
    const float* W_d2s  = (const float*)d_in[13];
    const float* as_d2s = (const float*)d_in[14];
    const float* ad_d2s = (const float*)d_in[15];
    const float* b_d2s  = (const float*)d_in[16];
    const float* W_ct_src = (const float*)d_in[17];
    const float* W_ct_dst = (const float*)d_in[18];
    const float* as_ct  = (const float*)d_in[19];
    const float* ad_ct  = (const float*)d_in[20];
    const float* b_ct   = (const float*)d_in[21];
    const float* W_out  = (const float*)d_in[22];
    const float* b_out  = (const float*)d_in[23];
    float* out = (float*)d_out;

    const int* tt_src = ei_tt;
    const int* tt_dst = ei_tt + E_TT;

    // ---- workspace carve-up (units: fp32 slots) ----
    float* ws = (float*)d_ws;
    size_t o = 0;
    ushort* htb = (ushort*)(ws + o);   o += (size_t)NT * 128;   // NT*256 bf16
    ushort* Pb1 = (ushort*)(ws + o);   o += (size_t)NT * 128;
    ushort* Pb2 = (ushort*)(ws + o);   o += (size_t)NT * 128;
    ushort* hcb = (ushort*)(ws + o);   o += (size_t)NC * 128;
    ushort* PSb = (ushort*)(ws + o);   o += (size_t)NC * 128;
    ushort* xtb = (ushort*)(ws + o);   o += (size_t)NT * 64;    // NT*128 bf16
    ushort* xcb = (ushort*)(ws + o);   o += (size_t)NC * 32;
    int* bktA = (int*)(ws + o);        o += (size_t)NT * CAP;   // int payload
    int* bktB = (int*)(ws + o);        o += (size_t)NT * CAP;
    int* bktC = (int*)(ws + o);        o += (size_t)NT * CAP;
    float* aS1 = ws + o;               o += (size_t)NT * 4;
    float* aD1 = ws + o;               o += (size_t)NT * 4;
    float* aS2 = ws + o;               o += (size_t)NT * 4;
    float* aD2 = ws + o;               o += (size_t)NT * 4;
    float* aSc = ws + o;               o += (size_t)NT * 4;     // used: NC*4
    float* aDc = ws + o;               o += (size_t)NT * 4;
    int*   cntA = (int*)(ws + o);      o += (size_t)NT;
    int*   cntB = (int*)(ws + o);      o += (size_t)NT;
    int*   cntC = (int*)(ws + o);      o += (size_t)NT;
    float* wfold = ws + o;             o += 1024;
    ushort* WtT   = (ushort*)(ws + o); o += 128 * 256 / 2;
    ushort* WcT   = (ushort*)(ws + o); o += 64 * 256 / 2;
    ushort* Ws2dT = (ushort*)(ws + o); o += 256 * 256 / 2;
    ushort* Wd2sT = (ushort*)(ws + o); o += 256 * 256 / 2;
    ushort* WctsT = (ushort*)(ws + o); o += 256 * 256 / 2;
    ushort* WoutT = (ushort*)(ws + o); o += 256 * 256 / 2;
    (void)ws_size; (void)n_in; (void)out_size;

    const dim3 blk(256);
    const int gGat = (NT + 3) / 4;
    const int RS = (NT + NRANGE - 1) / NRANGE;   // node-range size per XCD
    const int gxT = (NT + 127) / 128;            // 128-row GEMM tiles over NT
    const int gxA = (NT * 4 + 255) / 256;        // alpha segment blocks

    // 0) zero bucket counters (A,B,C contiguous)
    hipMemsetAsync(cntA, 0, (size_t)NT * 3 * sizeof(int), stream);

    // 1) prep: casts + 6 weight transposes + fold_ct, one launch
    const int s0 = NT * 32;            // x_target float4 count
    const int s1 = s0 + NC * 16;       // x_context
    const int s2 = s1 + 128 * 256;     // Wt
    const int s3 = s2 + 64 * 256;      // Wc
    const int s4 = s3 + 65536;         // W_s2d
    const int s5 = s4 + 65536;         // W_d2s
    const int s6 = s5 + 65536;         // W_ct_src
    const int s7 = s6 + 65536;         // W_out
    const int s8 = s7 + 1024;          // fold_ct
    hipLaunchKernelGGL(prep_all, dim3((s8 + 255) / 256), blk, 0, stream,
                       x_target, xtb, x_context, xcb,
                       Wt, WtT, Wc, WcT, W_s2d, Ws2dT, W_d2s, Wd2sT,
                       W_ct_src, WctsT, W_out, WoutT,
                       W_ct_dst, ad_ct, wfold,
                       s0, s1, s2, s3, s4, s5, s6, s7, s8);

    // 2) topology buckets (tt + ct in one launch)
    hipLaunchKernelGGL(build_all_buckets, dim3(1024), blk, 0, stream,
                       tt_src, tt_dst, E_TT, ei_ct_src, ei_ct_dst, E_CT, RS,
                       cntA, bktA, cntB, bktB, cntC, bktC);

    // 3) pretransforms (target + context in one launch)
    hipLaunchKernelGGL(gemm_pre2, dim3(gxT, 8), blk, 0, stream,
                       xtb, WtT, bt, htb, NT, xcb, WcT, bc, hcb, NC);

    // 4) projections + attn dots + ct-dst alphas, one launch
    hipLaunchKernelGGL(gemm_proj3, dim3(gxA, 13), blk, 0, stream,
                       htb, hcb, Ws2dT, Wd2sT, WctsT, Pb1, Pb2, PSb,
                       as_s2d, ad_s2d, as_d2s, ad_d2s, as_ct,
                       aS1, aD1, aS2, aD2, aSc, wfold, aDc, NT, NC);

    // 5) single fused gather: s2d + d2s + ct + skip + relu + bf16 cast
    hipLaunchKernelGGL(gat_gather_fused, dim3(gGat), blk, 0, stream,
                       cntA, bktA, aS1, aD1, Pb1, b_s2d,
                       cntB, bktB, aS2, aD2, Pb2, b_d2s,
                       cntC, bktC, aSc, aDc, PSb, b_ct,
                       htb, NT);

    // 6) final linear
    hipLaunchKernelGGL(gemm_bf16, dim3(gxT, 4), blk, 0, stream,
                       htb, WoutT, b_out, out, nullptr, NT, 256, 0);
}

// Round 8
// 404.544 us; speedup vs baseline: 1.0209x; 1.0209x over previous
//
#include <hip/hip_runtime.h>
#include <hip/hip_bf16.h>
#include <cstdint>
#include <cstddef>

// ---------------------------------------------------------------------------
// STGNN forward. Round 13: software-pipelined GEMM core (R12 otherwise).
//  - R12 post-mortem: 128x64 retile + merges net neutral (405->413). Root
//    cause of GEMM inefficiency identified: loads issued right before the
//    barrier -> every K-step exposes full HBM latency serially (~75% stall).
//  - New core: double-buffered LDS + register-staged prefetch. Per K-step:
//    issue t+1 loads to regs -> ds_read + 8 MFMA on tile t -> ds_write regs
//    to buf^1 -> ONE barrier. Latency hides under MFMA; barriers halved.
//    (Guide T3-minimum/T14 pattern.) LDS 30.7KB, ~80 VGPR.
//  - Gather / buckets / prep / launch structure untouched (proven form).
// ---------------------------------------------------------------------------

#define LRELU_SLOPE 0.2f
#define CAP 64
#define NRANGE 8

typedef __attribute__((ext_vector_type(8))) short short8;
typedef __attribute__((ext_vector_type(4))) float floatx4;

__device__ __forceinline__ float bf2f(ushort u) {
    union { unsigned int u32; float f; } v; v.u32 = ((unsigned int)u) << 16; return v.f;
}
__device__ __forceinline__ ushort f2bf(float x) {
    union { float f; unsigned int u; } v; v.f = x;
    unsigned int r = (v.u + 0x7FFFu + ((v.u >> 16) & 1u)) >> 16;
    return (ushort)r;
}

// ---- prep_all: casts | 6x weight transpose | fold_ct, one segmented grid ---
__global__ __launch_bounds__(256) void prep_all(
    const float* __restrict__ xt, ushort* __restrict__ xtb,
    const float* __restrict__ xc, ushort* __restrict__ xcb,
    const float* __restrict__ Wt,  ushort* __restrict__ WtT,
    const float* __restrict__ Wc,  ushort* __restrict__ WcT,
    const float* __restrict__ W1,  ushort* __restrict__ W1T,
    const float* __restrict__ W2,  ushort* __restrict__ W2T,
    const float* __restrict__ W3,  ushort* __restrict__ W3T,
    const float* __restrict__ W4,  ushort* __restrict__ W4T,
    const float* __restrict__ Wcd, const float* __restrict__ adc,
    float* __restrict__ wfold,
    int s0, int s1, int s2, int s3, int s4, int s5, int s6, int s7, int s8)
{
    const int idx = blockIdx.x * blockDim.x + threadIdx.x;
    if (idx < s0) {                       // x_target: float4 -> ushort4
        float4 v = ((const float4*)xt)[idx];
        ushort4 o;
        o.x = f2bf(v.x); o.y = f2bf(v.y); o.z = f2bf(v.z); o.w = f2bf(v.w);
        ((ushort4*)xtb)[idx] = o;
    } else if (idx < s1) {                // x_context
        const int i = idx - s0;
        float4 v = ((const float4*)xc)[i];
        ushort4 o;
        o.x = f2bf(v.x); o.y = f2bf(v.y); o.z = f2bf(v.z); o.w = f2bf(v.w);
        ((ushort4*)xcb)[i] = o;
    } else if (idx < s2) {                // Wt [128][256]
        const int i = idx - s1, k = i >> 8, n = i & 255;
        WtT[n * 128 + k] = f2bf(Wt[i]);
    } else if (idx < s3) {                // Wc [64][256]
        const int i = idx - s2, k = i >> 8, n = i & 255;
        WcT[n * 64 + k] = f2bf(Wc[i]);
    } else if (idx < s4) {                // W_s2d [256][256]
        const int i = idx - s3, k = i >> 8, n = i & 255;
        W1T[n * 256 + k] = f2bf(W1[i]);
    } else if (idx < s5) {                // W_d2s
        const int i = idx - s4, k = i >> 8, n = i & 255;
        W2T[n * 256 + k] = f2bf(W2[i]);
    } else if (idx < s6) {                // W_ct_src
        const int i = idx - s5, k = i >> 8, n = i & 255;
        W3T[n * 256 + k] = f2bf(W3[i]);
    } else if (idx < s7) {                // W_out
        const int i = idx - s6, k = i >> 8, n = i & 255;
        W4T[n * 256 + k] = f2bf(W4[i]);
    } else if (idx < s8) {                // fold_ct: wfold[k,h]
        const int i = idx - s7, k = i >> 2, h = i & 3;
        float s = 0.f;
#pragma unroll 8
        for (int c = 0; c < 64; ++c)
            s += Wcd[(size_t)k * 256 + h * 64 + c] * adc[h * 64 + c];
        wfold[i] = s;
    }
}

// -------- bf16 MFMA GEMM core, 128x64 tile, double-buffered pipeline --------
// 4 waves; wave w owns rows 32w..32w+31 (8 MFMA per K-step). Tile t+1 loads
// issued to REGISTERS before computing tile t; ds_write to buf^1 after the
// MFMAs; ONE barrier per K-step (write buf != read buf -> no WAR barrier).
__device__ __forceinline__ void gemm_core(
    const ushort* __restrict__ A, const ushort* __restrict__ Bt,
    const float* __restrict__ bias, float* __restrict__ Cf,
    ushort* __restrict__ Cb, int M, int K, int do_relu,
    const float* __restrict__ attS, const float* __restrict__ attD,
    float* __restrict__ aSo, float* __restrict__ aDo,
    int row0, int col0)
{
    __shared__ short As[2][128][40];  // +8 pad
    __shared__ short Bs[2][64][40];
    const int tid  = threadIdx.x;
    const int ra = tid >> 1;            // A stage: 2 threads/row, 16 cols each
    const int ka = (tid & 1) * 16;
    const int rb = tid >> 2;            // B stage: 4 threads/row, 8 cols each
    const int kb = (tid & 3) * 8;
    const int w    = tid >> 6;
    const int lane = tid & 63;
    const int cix  = lane & 15;
    const int ksel = (lane >> 4) * 8;
    const bool arow_ok = (row0 + ra < M);
    const ushort* aptr = A + (size_t)(row0 + ra) * K + ka;
    const ushort* bptr = Bt + (size_t)(col0 + rb) * K + kb;

    floatx4 acc[2][4];
#pragma unroll
    for (int r = 0; r < 2; ++r)
#pragma unroll
        for (int c = 0; c < 4; ++c) acc[r][c] = (floatx4){0.f, 0.f, 0.f, 0.f};

    // prologue: stage tile 0
    short8 sa0 = {0,0,0,0,0,0,0,0}, sa1 = sa0, sb;
    if (arow_ok) { sa0 = *(const short8*)aptr; sa1 = *(const short8*)(aptr + 8); }
    sb = *(const short8*)bptr;
    *(short8*)&As[0][ra][ka]     = sa0;
    *(short8*)&As[0][ra][ka + 8] = sa1;
    *(short8*)&Bs[0][rb][kb]     = sb;
    __syncthreads();

    int cur = 0;
    for (int k0 = 0; k0 < K; k0 += 32) {
        const bool more = (k0 + 32 < K);
        if (more) {                       // issue t+1 loads (hide under MFMA)
            if (arow_ok) {
                sa0 = *(const short8*)(aptr + k0 + 32);
                sa1 = *(const short8*)(aptr + k0 + 40);
            }
            sb = *(const short8*)(bptr + k0 + 32);
        }
        const short8 af0 = *(const short8*)&As[cur][32 * w + cix][ksel];
        const short8 af1 = *(const short8*)&As[cur][32 * w + 16 + cix][ksel];
#pragma unroll
        for (int c = 0; c < 4; ++c) {
            const short8 bf = *(const short8*)&Bs[cur][16 * c + cix][ksel];
            acc[0][c] = __builtin_amdgcn_mfma_f32_16x16x32_bf16(af0, bf, acc[0][c], 0, 0, 0);
            acc[1][c] = __builtin_amdgcn_mfma_f32_16x16x32_bf16(af1, bf, acc[1][c], 0, 0, 0);
        }
        if (more) {                       // write staged regs to the OTHER buf
            *(short8*)&As[cur ^ 1][ra][ka]     = sa0;
            *(short8*)&As[cur ^ 1][ra][ka + 8] = sa1;
            *(short8*)&Bs[cur ^ 1][rb][kb]     = sb;
        }
        __syncthreads();
        cur ^= 1;
    }

#pragma unroll
    for (int r = 0; r < 2; ++r) {
        const int rbase = row0 + 32 * w + 16 * r + (lane >> 4) * 4;
#pragma unroll
        for (int c = 0; c < 4; ++c) {
            const int col = col0 + 16 * c + cix;
            const float bv = bias ? bias[col] : 0.f;
#pragma unroll
            for (int i = 0; i < 4; ++i) {
                const int row = rbase + i;
                if (row < M) {
                    float v = acc[r][c][i] + bv;
                    if (do_relu) v = fmaxf(v, 0.f);
                    const size_t off = (size_t)row * 256 + col;
                    if (Cf) Cf[off] = v;
                    if (Cb) Cb[off] = f2bf(v);
                }
            }
        }
    }

    // fused per-row attention dots (raw fp32 acc, pre-bias/relu)
    if (attS) {
        float sA[2][4], sD[2][4];
#pragma unroll
        for (int r = 0; r < 2; ++r)
#pragma unroll
            for (int i = 0; i < 4; ++i) { sA[r][i] = 0.f; sD[r][i] = 0.f; }
#pragma unroll
        for (int c = 0; c < 4; ++c) {
            const float as_v = attS[col0 + 16 * c + cix];
            const float ad_v = attD ? attD[col0 + 16 * c + cix] : 0.f;
#pragma unroll
            for (int r = 0; r < 2; ++r)
#pragma unroll
                for (int i = 0; i < 4; ++i) {
                    sA[r][i] += acc[r][c][i] * as_v;
                    sD[r][i] += acc[r][c][i] * ad_v;
                }
        }
#pragma unroll
        for (int off = 1; off < 16; off <<= 1) {
#pragma unroll
            for (int r = 0; r < 2; ++r)
#pragma unroll
                for (int i = 0; i < 4; ++i) {
                    sA[r][i] += __shfl_xor(sA[r][i], off);
                    sD[r][i] += __shfl_xor(sD[r][i], off);
                }
        }
        if (cix == 0) {
            const int head = col0 >> 6;
#pragma unroll
            for (int r = 0; r < 2; ++r) {
                const int rbase = row0 + 32 * w + 16 * r + (lane >> 4) * 4;
#pragma unroll
                for (int i = 0; i < 4; ++i) {
                    const int row = rbase + i;
                    if (row < M) {
                        aSo[(size_t)row * 4 + head] = sA[r][i];
                        if (aDo) aDo[(size_t)row * 4 + head] = sD[r][i];
                    }
                }
            }
        }
    }
}

// ---- standalone GEMM (final linear): grid (M/128, 4) -----------------------
__global__ __launch_bounds__(256) void gemm_bf16(
    const ushort* __restrict__ A, const ushort* __restrict__ Bt,
    const float* __restrict__ bias, float* __restrict__ Cf,
    ushort* __restrict__ Cb, int M, int K, int do_relu)
{
    const int row0 = blockIdx.x * 128;
    if (row0 >= M) return;
    gemm_core(A, Bt, bias, Cf, Cb, M, K, do_relu,
              nullptr, nullptr, nullptr, nullptr, row0, blockIdx.y * 64);
}

// ---- merged pretransforms: y<4 target (K=128), y>=4 context (K=64) ---------
__global__ __launch_bounds__(256) void gemm_pre2(
    const ushort* __restrict__ xtb, const ushort* __restrict__ WtT,
    const float* __restrict__ bt, ushort* __restrict__ htb, int NT,
    const ushort* __restrict__ xcb, const ushort* __restrict__ WcT,
    const float* __restrict__ bc, ushort* __restrict__ hcb, int NC)
{
    const int y = blockIdx.y;
    const int row0 = blockIdx.x * 128;
    if (y < 4) {
        if (row0 >= NT) return;
        gemm_core(xtb, WtT, bt, nullptr, htb, NT, 128, 1,
                  nullptr, nullptr, nullptr, nullptr, row0, y * 64);
    } else {
        if (row0 >= NC) return;
        gemm_core(xcb, WcT, bc, nullptr, hcb, NC, 64, 1,
                  nullptr, nullptr, nullptr, nullptr, row0, (y - 4) * 64);
    }
}

// ---- merged projections: y<4 s2d | y<8 d2s | y<12 ct-src | y==12 alpha -----
__global__ __launch_bounds__(256) void gemm_proj3(
    const ushort* __restrict__ htb, const ushort* __restrict__ hcb,
    const ushort* __restrict__ W1T, const ushort* __restrict__ W2T,
    const ushort* __restrict__ W3T,
    ushort* __restrict__ Pb1, ushort* __restrict__ Pb2, ushort* __restrict__ PSb,
    const float* __restrict__ as1, const float* __restrict__ ad1,
    const float* __restrict__ as2, const float* __restrict__ ad2,
    const float* __restrict__ asc,
    float* __restrict__ aS1, float* __restrict__ aD1,
    float* __restrict__ aS2, float* __restrict__ aD2,
    float* __restrict__ aSc,
    const float* __restrict__ wfold, float* __restrict__ aDc,
    int NT, int NC)
{
    const int y = blockIdx.y;
    if (y == 12) {
        // alpha_from_fold: aDc[n,h] = htb[n,:] . wfold[:,h]
        __shared__ float wf[1024];
        const int tid = threadIdx.x;
        *(float4*)&wf[tid * 4] = *(const float4*)&wfold[tid * 4];
        __syncthreads();
        const int idx = blockIdx.x * 256 + tid;
        if (idx >= NT * 4) return;
        const int n = idx >> 2, h = idx & 3;
        const ushort* row = htb + (size_t)n * 256;
        float s = 0.f;
#pragma unroll
        for (int k = 0; k < 256; k += 4) {
            ushort4 r4 = *(const ushort4*)(row + k);
            s += bf2f(r4.x) * wf[(k + 0) * 4 + h] + bf2f(r4.y) * wf[(k + 1) * 4 + h]
               + bf2f(r4.z) * wf[(k + 2) * 4 + h] + bf2f(r4.w) * wf[(k + 3) * 4 + h];
        }
        aDc[idx] = s;
        return;
    }
    const int row0 = blockIdx.x * 128;
    if (y < 4) {
        if (row0 >= NT) return;
        gemm_core(htb, W1T, nullptr, nullptr, Pb1, NT, 256, 0,
                  as1, ad1, aS1, aD1, row0, y * 64);
    } else if (y < 8) {
        if (row0 >= NT) return;
        gemm_core(htb, W2T, nullptr, nullptr, Pb2, NT, 256, 0,
                  as2, ad2, aS2, aD2, row0, (y - 4) * 64);
    } else {
        if (row0 >= NC) return;
        gemm_core(hcb, W3T, nullptr, nullptr, PSb, NC, 256, 0,
                  asc, nullptr, aSc, nullptr, row0, (y - 8) * 64);
    }
}

// ---- merged topology bucket build: blocks [0,512) tt, [512,1024) ct --------
// XCD-range-partitioned (range = bx&7), int payload (partner node only).
__global__ __launch_bounds__(256) void build_all_buckets(
    const int* __restrict__ tt_src, const int* __restrict__ tt_dst, int E_tt,
    const int* __restrict__ ct_src, const int* __restrict__ ct_dst, int E_ct,
    int RS,
    int* __restrict__ cntA, int* __restrict__ bktA,
    int* __restrict__ cntB, int* __restrict__ bktB,
    int* __restrict__ cntC, int* __restrict__ bktC)
{
    const int bx = (blockIdx.x < 512) ? blockIdx.x : blockIdx.x - 512;
    const int range = bx & (NRANGE - 1);
    const int lo = range * RS, hi = lo + RS;
    const int j  = bx >> 3;                  // 64 blocks per range
    const int stride = 64 * blockDim.x;
    if (blockIdx.x < 512) {
        for (int e = j * blockDim.x + threadIdx.x; e < E_tt; e += stride) {
            const int s = tt_src[e], d = tt_dst[e];
            if (d >= lo && d < hi) {
                const int pa = atomicAdd(&cntA[d], 1);
                if (pa < CAP) bktA[(size_t)d * CAP + pa] = s;
            }
            if (s >= lo && s < hi) {
                const int pb = atomicAdd(&cntB[s], 1);
                if (pb < CAP) bktB[(size_t)s * CAP + pb] = d;
            }
        }
    } else {
        for (int e = j * blockDim.x + threadIdx.x; e < E_ct; e += stride) {
            const int s = ct_src[e], d = ct_dst[e];
            if (d >= lo && d < hi) {
                const int p = atomicAdd(&cntC[d], 1);
                if (p < CAP) bktC[(size_t)d * CAP + p] = s;
            }
        }
    }
}

// ---- one GAT accumulation phase (R7 verbatim; inlined 3x in fused gather) --
__device__ __forceinline__ void gat_phase(
    int n, int h, int c4,
    const int* __restrict__ cnt, const int* __restrict__ bkt,
    const float* __restrict__ aS, const float* __restrict__ aD,
    const ushort* __restrict__ X, const float* __restrict__ bias,
    float scale, int has_self, float4& out)
{
    const float aDn = aD[(size_t)n * 4 + h];
    float4 f = {0.f, 0.f, 0.f, 0.f};
    float den = 0.f;
    if (has_self) {
        float a = aS[(size_t)n * 4 + h] + aDn;
        a = (a >= 0.f) ? a : LRELU_SLOPE * a;
        const float w = __expf(a);
        const ushort4 x = *(const ushort4*)(X + (size_t)n * 256 + c4);
        f.x = w * bf2f(x.x); f.y = w * bf2f(x.y);
        f.z = w * bf2f(x.z); f.w = w * bf2f(x.w);
        den = w;
    }
    const int deg = min(cnt[n], CAP);
    const int* b = bkt + (size_t)n * CAP;
    int i = 0;
    for (; i + 4 <= deg; i += 4) {
        const int s0 = b[i], s1 = b[i + 1], s2 = b[i + 2], s3 = b[i + 3];
        float a0 = aS[(size_t)s0 * 4 + h] + aDn;
        float a1 = aS[(size_t)s1 * 4 + h] + aDn;
        float a2 = aS[(size_t)s2 * 4 + h] + aDn;
        float a3 = aS[(size_t)s3 * 4 + h] + aDn;
        a0 = (a0 >= 0.f) ? a0 : LRELU_SLOPE * a0;
        a1 = (a1 >= 0.f) ? a1 : LRELU_SLOPE * a1;
        a2 = (a2 >= 0.f) ? a2 : LRELU_SLOPE * a2;
        a3 = (a3 >= 0.f) ? a3 : LRELU_SLOPE * a3;
        const float w0 = __expf(a0), w1 = __expf(a1);
        const float w2 = __expf(a2), w3 = __expf(a3);
        const ushort4 x0 = *(const ushort4*)(X + (size_t)s0 * 256 + c4);
        const ushort4 x1 = *(const ushort4*)(X + (size_t)s1 * 256 + c4);
        const ushort4 x2 = *(const ushort4*)(X + (size_t)s2 * 256 + c4);
        const ushort4 x3 = *(const ushort4*)(X + (size_t)s3 * 256 + c4);
        f.x += w0 * bf2f(x0.x) + w1 * bf2f(x1.x) + w2 * bf2f(x2.x) + w3 * bf2f(x3.x);
        f.y += w0 * bf2f(x0.y) + w1 * bf2f(x1.y) + w2 * bf2f(x2.y) + w3 * bf2f(x3.y);
        f.z += w0 * bf2f(x0.z) + w1 * bf2f(x1.z) + w2 * bf2f(x2.z) + w3 * bf2f(x3.z);
        f.w += w0 * bf2f(x0.w) + w1 * bf2f(x1.w) + w2 * bf2f(x2.w) + w3 * bf2f(x3.w);
        den += w0 + w1 + w2 + w3;
    }
    for (; i < deg; ++i) {
        const int s = b[i];
        float a = aS[(size_t)s * 4 + h] + aDn;
        a = (a >= 0.f) ? a : LRELU_SLOPE * a;
        const float w = __expf(a);
        const ushort4 x = *(const ushort4*)(X + (size_t)s * 256 + c4);
        f.x += w * bf2f(x.x); f.y += w * bf2f(x.y);
        f.z += w * bf2f(x.z); f.w += w * bf2f(x.w);
        den += w;
    }
    const float inv = 1.f / fmaxf(den, 1e-16f);
    const float4 bv = *(const float4*)(bias + c4);
    out.x += scale * (f.x * inv + bv.x);
    out.y += scale * (f.y * inv + bv.y);
    out.z += scale * (f.z * inv + bv.z);
    out.w += scale * (f.w * inv + bv.w);
}

// ---- fused gather: all 3 GATs + skip + relu + bf16 cast, one wave/node -----
__global__ __launch_bounds__(256) void gat_gather_fused(
    const int* __restrict__ cntA, const int* __restrict__ bktA,
    const float* __restrict__ aS1, const float* __restrict__ aD1,
    const ushort* __restrict__ P1, const float* __restrict__ b1,
    const int* __restrict__ cntB, const int* __restrict__ bktB,
    const float* __restrict__ aS2, const float* __restrict__ aD2,
    const ushort* __restrict__ P2, const float* __restrict__ b2,
    const int* __restrict__ cntC, const int* __restrict__ bktC,
    const float* __restrict__ aSc, const float* __restrict__ aDc,
    const ushort* __restrict__ Pc, const float* __restrict__ b3,
    ushort* __restrict__ htb, int N)
{
    const int n = blockIdx.x * 4 + (threadIdx.x >> 6);
    if (n >= N) return;
    const int lane = threadIdx.x & 63;
    const int h  = lane >> 4;          // 16 lanes per head
    const int c4 = lane << 2;          // channel base, 0..252

    float4 out = {0.f, 0.f, 0.f, 0.f};
    gat_phase(n, h, c4, cntA, bktA, aS1, aD1, P1, b1, 0.25f, 1, out);
    gat_phase(n, h, c4, cntB, bktB, aS2, aD2, P2, b2, 0.25f, 1, out);
    gat_phase(n, h, c4, cntC, bktC, aSc, aDc, Pc, b3, 0.50f, 0, out);

    ushort* hp = htb + (size_t)n * 256 + c4;
    const ushort4 hb = *(const ushort4*)hp;
    ushort4 o;
    o.x = f2bf(fmaxf(out.x + bf2f(hb.x), 0.f));
    o.y = f2bf(fmaxf(out.y + bf2f(hb.y), 0.f));
    o.z = f2bf(fmaxf(out.z + bf2f(hb.z), 0.f));
    o.w = f2bf(fmaxf(out.w + bf2f(hb.w), 0.f));
    *(ushort4*)hp = o;
}

// ---------------------------------------------------------------------------
extern "C" void kernel_launch(void* const* d_in, const int* in_sizes, int n_in,
                              void* d_out, int out_size, void* d_ws, size_t ws_size,
                              hipStream_t stream)
{
    const int NT   = in_sizes[0] / 128;
    const int NC   = in_sizes[1] / 64;
    const int E_TT = in_sizes[2] / 2;
    const int E_CT = in_sizes[3];

    const float* x_target = (const float*)d_in[0];
    const float* x_context= (const float*)d_in[1];
    const int*   ei_tt    = (const int*)d_in[2];
    const int*   ei_ct_src= (const int*)d_in[3];
    const int*   ei_ct_dst= (const int*)d_in[4];
    const float* Wt   = (const float*)d_in[5];
    const float* bt   = (const float*)d_in[6];
    const float* Wc   = (const float*)d_in[7];
    const float* bc   = (const float*)d_in[8];
    const float* W_s2d  = (const float*)d_in[9];
    const float* as_s2d = (const float*)d_in[10];
    const float* ad_s2d = (const float*)d_in[11];
    const float* b_s2d  = (const float*)d_in[12];
    const float* W_d2s  = (const float*)d_in[13];
    const float* as_d2s = (const float*)d_in[14];
    const float* ad_d2s = (const float*)d_in[15];
    const float* b_d2s  = (const float*)d_in[16];
    const float* W_ct_src = (const float*)d_in[17];
    const float* W_ct_dst = (const float*)d_in[18];
    const float* as_ct  = (const float*)d_in[19];
    const float* ad_ct  = (const float*)d_in[20];
    const float* b_ct   = (const float*)d_in[21];
    const float* W_out  = (const float*)d_in[22];
    const float* b_out  = (const float*)d_in[23];
    float* out = (float*)d_out;

    const int* tt_src = ei_tt;
    const int* tt_dst = ei_tt + E_TT;

    // ---- workspace carve-up (units: fp32 slots) ----
    float* ws = (float*)d_ws;
    size_t o = 0;
    ushort* htb = (ushort*)(ws + o);   o += (size_t)NT * 128;   // NT*256 bf16
    ushort* Pb1 = (ushort*)(ws + o);   o += (size_t)NT * 128;
    ushort* Pb2 = (ushort*)(ws + o);   o += (size_t)NT * 128;
    ushort* hcb = (ushort*)(ws + o);   o += (size_t)NC * 128;
    ushort* PSb = (ushort*)(ws + o);   o += (size_t)NC * 128;
    ushort* xtb = (ushort*)(ws + o);   o += (size_t)NT * 64;    // NT*128 bf16
    ushort* xcb = (ushort*)(ws + o);   o += (size_t)NC * 32;
    int* bktA = (int*)(ws + o);        o += (size_t)NT * CAP;   // int payload
    int* bktB = (int*)(ws + o);        o += (size_t)NT * CAP;
    int* bktC = (int*)(ws + o);        o += (size_t)NT * CAP;
    float* aS1 = ws + o;               o += (size_t)NT * 4;
    float* aD1 = ws + o;               o += (size_t)NT * 4;
    float* aS2 = ws + o;               o += (size_t)NT * 4;
    float* aD2 = ws + o;               o += (size_t)NT * 4;
    float* aSc = ws + o;               o += (size_t)NT * 4;     // used: NC*4
    float* aDc = ws + o;               o += (size_t)NT * 4;
    int*   cntA = (int*)(ws + o);      o += (size_t)NT;
    int*   cntB = (int*)(ws + o);      o += (size_t)NT;
    int*   cntC = (int*)(ws + o);      o += (size_t)NT;
    float* wfold = ws + o;             o += 1024;
    ushort* WtT   = (ushort*)(ws + o); o += 128 * 256 / 2;
    ushort* WcT   = (ushort*)(ws + o); o += 64 * 256 / 2;
    ushort* Ws2dT = (ushort*)(ws + o); o += 256 * 256 / 2;
    ushort* Wd2sT = (ushort*)(ws + o); o += 256 * 256 / 2;
    ushort* WctsT = (ushort*)(ws + o); o += 256 * 256 / 2;
    ushort* WoutT = (ushort*)(ws + o); o += 256 * 256 / 2;
    (void)ws_size; (void)n_in; (void)out_size;

    const dim3 blk(256);
    const int gGat = (NT + 3) / 4;
    const int RS = (NT + NRANGE - 1) / NRANGE;   // node-range size per XCD
    const int gxT = (NT + 127) / 128;            // 128-row GEMM tiles over NT
    const int gxA = (NT * 4 + 255) / 256;        // alpha segment blocks

    // 0) zero bucket counters (A,B,C contiguous)
    hipMemsetAsync(cntA, 0, (size_t)NT * 3 * sizeof(int), stream);

    // 1) prep: casts + 6 weight transposes + fold_ct, one launch
    const int s0 = NT * 32;            // x_target float4 count
    const int s1 = s0 + NC * 16;       // x_context
    const int s2 = s1 + 128 * 256;     // Wt
    const int s3 = s2 + 64 * 256;      // Wc
    const int s4 = s3 + 65536;         // W_s2d
    const int s5 = s4 + 65536;         // W_d2s
    const int s6 = s5 + 65536;         // W_ct_src
    const int s7 = s6 + 65536;         // W_out
    const int s8 = s7 + 1024;          // fold_ct
    hipLaunchKernelGGL(prep_all, dim3((s8 + 255) / 256), blk, 0, stream,
                       x_target, xtb, x_context, xcb,
                       Wt, WtT, Wc, WcT, W_s2d, Ws2dT, W_d2s, Wd2sT,
                       W_ct_src, WctsT, W_out, WoutT,
                       W_ct_dst, ad_ct, wfold,
                       s0, s1, s2, s3, s4, s5, s6, s7, s8);

    // 2) topology buckets (tt + ct in one launch)
    hipLaunchKernelGGL(build_all_buckets, dim3(1024), blk, 0, stream,
                       tt_src, tt_dst, E_TT, ei_ct_src, ei_ct_dst, E_CT, RS,
                       cntA, bktA, cntB, bktB, cntC, bktC);

    // 3) pretransforms (target + context in one launch)
    hipLaunchKernelGGL(gemm_pre2, dim3(gxT, 8), blk, 0, stream,
                       xtb, WtT, bt, htb, NT, xcb, WcT, bc, hcb, NC);

    // 4) projections + attn dots + ct-dst alphas, one launch
    hipLaunchKernelGGL(gemm_proj3, dim3(gxA, 13), blk, 0, stream,
                       htb, hcb, Ws2dT, Wd2sT, WctsT, Pb1, Pb2, PSb,
                       as_s2d, ad_s2d, as_d2s, ad_d2s, as_ct,
                       aS1, aD1, aS2, aD2, aSc, wfold, aDc, NT, NC);

    // 5) single fused gather: s2d + d2s + ct + skip + relu + bf16 cast
    hipLaunchKernelGGL(gat_gather_fused, dim3(gGat), blk, 0, stream,
                       cntA, bktA, aS1, aD1, Pb1, b_s2d,
                       cntB, bktB, aS2, aD2, Pb2, b_d2s,
                       cntC, bktC, aSc, aDc, PSb, b_ct,
                       htb, NT);

    // 6) final linear
    hipLaunchKernelGGL(gemm_bf16, dim3(gxT, 4), blk, 0, stream,
                       htb, WoutT, b_out, out, nullptr, NT, 256, 0);
}